// Round 12
// baseline (2154.394 us; speedup 1.0000x reference)
//
#include <hip/hip_runtime.h>
#include <cstddef>
#include <cstdint>

#define NN 50000
#define NE 800000
#define CH 128

// counting-sort geometry
#define NBUCK 782                 // ceil(50000/64) buckets of 64 cols
#define BH 800                    // kC blocks (3/CU for latency hiding)
#define EPB 1000                  // edges per kC block (800*1000 = 800000)
#define MH (NBUCK * BH)           // 625600 hist entries
#define G1 ((MH + 255) / 256)     // 2444 scan blocks
#define S2R ((G1 + 255) / 256)    // 10 scan2 rounds

// deg (row-degree) filtered-histogram geometry
#define DR 8                      // row ranges
#define DRS 6250                  // rows per range (8*6250 = 50000)
#define DC 50                     // edge chunks
#define DCE 16000                 // edges per chunk (50*16000 = 800000)
#define DBLK 448                  // swizzled: 7*8*8 (48 idle)

#define FIXS 8388608.0f           // 2^23 fixed-point scale for deg accumulation

// k_front block layout: [0,DBLK) deg | [DBLK,DBLK+BH) col-hist | rest conv
#define XB_BLOCKS 12500           // NN*64 pairs / 256
#define FRONT_BLOCKS (DBLK + BH + XB_BLOCKS + 80)

typedef unsigned int u32;
typedef unsigned short u16;
typedef unsigned long long u64;
typedef __attribute__((ext_vector_type(4))) unsigned int u32x4;
typedef __attribute__((ext_vector_type(8))) unsigned short u16x8;
typedef __attribute__((ext_vector_type(8))) __bf16 bf16x8;
typedef __attribute__((ext_vector_type(4))) float f32x4;

// ---------------- bf16 helpers ----------------
__device__ __forceinline__ u32 bf_rne(float f) {
  u32 u = __float_as_uint(f);
  return (u + 0x7FFFu + ((u >> 16) & 1u)) >> 16;
}
__device__ __forceinline__ u32 pack_bf2(float lo, float hi) {
  return bf_rne(lo) | (bf_rne(hi) << 16);
}
__device__ __forceinline__ float bflo(u32 v) { return __uint_as_float(v << 16); }
__device__ __forceinline__ float bfhi(u32 v) { return __uint_as_float(v & 0xFFFF0000u); }

// ---------------- scan helpers ----------------
__device__ __forceinline__ int wave_scan_incl(int v) {
  int lane = threadIdx.x & 63;
#pragma unroll
  for (int d = 1; d < 64; d <<= 1) {
    int u = __shfl_up(v, d, 64);
    if (lane >= d) v += u;
  }
  return v;
}

__device__ __forceinline__ int block_scan_incl(int v, int* wsum) {
  int t = threadIdx.x, lane = t & 63, wid = t >> 6;
  int incl = wave_scan_incl(v);
  if (lane == 63) wsum[wid] = incl;
  __syncthreads();
  int add = 0;
#pragma unroll
  for (int w = 0; w < 3; ++w) add += (w < wid) ? wsum[w] : 0;
  return incl + add;
}

// ---------------- k_front: row-deg + col-hist + conversions in one launch ----------------
__global__ __launch_bounds__(256) void k_front(const int* __restrict__ ei, const float* __restrict__ ew,
                                               int* __restrict__ part, int* __restrict__ hist,
                                               const float* __restrict__ x, u32* __restrict__ xb,
                                               const float* __restrict__ W0, const float* __restrict__ W1,
                                               const float* __restrict__ W2, const float* __restrict__ W3,
                                               u16* __restrict__ Wp) {
  __shared__ u32 smem[DRS];       // deg: full; hist: first NBUCK
  const int bid = blockIdx.x;
  const int t = threadIdx.x;

  if (bid < DBLK) {
    // ---- row degree (vec4, XCD-swizzled: chunk c on XCD c%8) ----
    const int low3 = bid & 7;
    const int q = bid >> 3;
    const int r = q & 7;
    const int chi = q >> 3;
    const int c = chi * 8 + low3;
    if (c >= DC) return;
    for (int i = t; i < DRS; i += 256) smem[i] = 0u;
    __syncthreads();
    const int base = r * DRS;
    const int4* rows4 = (const int4*)(ei + c * DCE);
    const float4* ws4 = (const float4*)(ew + c * DCE);
    for (int v = t; v < DCE / 4; v += 256) {
      int4 rv = rows4[v];
      float4 wv = ws4[v];
      unsigned rel;
      rel = (unsigned)(rv.x - base); if (rel < (unsigned)DRS) atomicAdd(&smem[rel], (u32)(wv.x * FIXS + 0.5f));
      rel = (unsigned)(rv.y - base); if (rel < (unsigned)DRS) atomicAdd(&smem[rel], (u32)(wv.y * FIXS + 0.5f));
      rel = (unsigned)(rv.z - base); if (rel < (unsigned)DRS) atomicAdd(&smem[rel], (u32)(wv.z * FIXS + 0.5f));
      rel = (unsigned)(rv.w - base); if (rel < (unsigned)DRS) atomicAdd(&smem[rel], (u32)(wv.w * FIXS + 0.5f));
    }
    __syncthreads();
    int* dst = part + (size_t)c * NN + base;
    for (int i = t; i < DRS; i += 256) dst[i] = (int)smem[i];
    return;
  }

  if (bid < DBLK + BH) {
    // ---- col-bucket histogram for kC sub-chunk b ----
    const int b = bid - DBLK;
    int* ch = (int*)smem;
    for (int i = t; i < NBUCK; i += 256) ch[i] = 0;
    __syncthreads();
    const int4* cols4 = (const int4*)(ei + NE + b * EPB);
    for (int v = t; v < EPB / 4; v += 256) {
      int4 cv = cols4[v];
      atomicAdd(&ch[cv.x >> 6], 1);
      atomicAdd(&ch[cv.y >> 6], 1);
      atomicAdd(&ch[cv.z >> 6], 1);
      atomicAdd(&ch[cv.w >> 6], 1);
    }
    __syncthreads();
    for (int i = t; i < NBUCK; i += 256) hist[i * BH + b] = ch[i];
    return;
  }

  const int c2 = bid - (DBLK + BH);
  if (c2 < XB_BLOCKS) {
    // ---- x -> bf16 pairs ----
    int i = c2 * 256 + t;
    if (i < NN * 64) {
      float2 f = ((const float2*)x)[i];
      xb[i] = pack_bf2(f.x, f.y);
    }
    return;
  }
  // ---- weight pack (MFMA B-fragment layout) ----
  int tt = (c2 - XB_BLOCKS) * 256 + t;
  if (tt >= 10 * 4 * 8 * 64) return;
  int lane = tt & 63, cb = (tt >> 6) & 7, kb = (tt >> 9) & 3, m = tt >> 11;
  const float* Wb; int io;
  if (m == 0)      { Wb = W0; io = 0; }
  else if (m < 3)  { Wb = W1; io = m - 1; }
  else if (m < 6)  { Wb = W2; io = m - 3; }
  else             { Wb = W3; io = m - 6; }
  const float* s = Wb + (size_t)io * CH * CH;
  int c  = cb * 16 + (lane & 15);
  int k0 = kb * 32 + (lane >> 4) * 8;
  u16* o = Wp + (size_t)tt * 8;
#pragma unroll
  for (int e = 0; e < 8; ++e) o[e] = (u16)bf_rne(s[(k0 + e) * CH + c]);
}

__global__ __launch_bounds__(256) void k_scan1(const int* __restrict__ hist, int* __restrict__ partials) {
  __shared__ int wsum[4];
  int i = blockIdx.x * 256 + threadIdx.x;
  int v = (i < MH) ? hist[i] : 0;
  int incl = block_scan_incl(v, wsum);
  if (threadIdx.x == 255) partials[blockIdx.x] = incl;
}

__global__ __launch_bounds__(256) void k_scan2(int* __restrict__ partials) {
  __shared__ int wsum[4];
  __shared__ int carrys;
  const int t = threadIdx.x;
  int carry = 0;
#pragma unroll
  for (int r = 0; r < S2R; ++r) {
    int idx = r * 256 + t;
    int v = (idx < G1) ? partials[idx] : 0;
    int incl = block_scan_incl(v, wsum);
    if (idx < G1) partials[idx] = carry + incl - v;   // exclusive
    if (t == 255) carrys = incl;
    __syncthreads();
    carry += carrys;
    __syncthreads();
  }
}

// k_mid: scan3 (blocks [0,G1)) + degred (blocks [G1, G1+196))
__global__ __launch_bounds__(256) void k_mid(int* __restrict__ hist, const int* __restrict__ partials,
                                             const int* __restrict__ part, float* __restrict__ dis) {
  __shared__ int wsum[4];
  const int bid = blockIdx.x;
  if (bid < G1) {
    int i = bid * 256 + threadIdx.x;
    int v = (i < MH) ? hist[i] : 0;
    int incl = block_scan_incl(v, wsum);
    if (i < MH) hist[i] = incl - v + partials[bid];   // exclusive, in place
    return;
  }
  int i = (bid - G1) * 256 + threadIdx.x;
  if (i >= NN) return;
  int s = 0;
#pragma unroll 10
  for (int c = 0; c < DC; ++c) s += part[(size_t)c * NN + i];
  dis[i] = (s > 0) ? rsqrtf((float)s * (1.0f / FIXS)) : 0.f;
}

// kC: place edges into bucket regions with FULLY NORMALIZED weight folded in.
// record = {w:f32, col:u16, src:u16}; within-bucket order is arbitrary (prop
// accumulates in LDS, no per-col sort needed anymore).
__global__ __launch_bounds__(256) void kC(const int* __restrict__ ei, const float* __restrict__ ew,
                                          const int* __restrict__ excl, const float* __restrict__ dis,
                                          u64* __restrict__ meta) {
  __shared__ int lbase[NBUCK];
  __shared__ int lcnt[NBUCK];
  const int b = blockIdx.x, t = threadIdx.x;
  for (int i = t; i < NBUCK; i += 256) { lbase[i] = excl[i * BH + b]; lcnt[i] = 0; }
  __syncthreads();
  const int e0 = b * EPB;
  const int4* srcs4 = (const int4*)(ei + e0);
  const int4* cols4 = (const int4*)(ei + NE + e0);
  const float4* ws4 = (const float4*)(ew + e0);
  for (int v = t; v < EPB / 4; v += 256) {
    int4 sv = srcs4[v];
    int4 cv = cols4[v];
    float4 wv = ws4[v];
    int bk, rk; float w;
    w = wv.x * dis[sv.x] * dis[cv.x];
    bk = cv.x >> 6; rk = atomicAdd(&lcnt[bk], 1);
    meta[lbase[bk] + rk] = ((u64)__float_as_uint(w) << 32) | ((u32)cv.x << 16) | (u32)sv.x;
    w = wv.y * dis[sv.y] * dis[cv.y];
    bk = cv.y >> 6; rk = atomicAdd(&lcnt[bk], 1);
    meta[lbase[bk] + rk] = ((u64)__float_as_uint(w) << 32) | ((u32)cv.y << 16) | (u32)sv.y;
    w = wv.z * dis[sv.z] * dis[cv.z];
    bk = cv.z >> 6; rk = atomicAdd(&lcnt[bk], 1);
    meta[lbase[bk] + rk] = ((u64)__float_as_uint(w) << 32) | ((u32)cv.z << 16) | (u32)sv.z;
    w = wv.w * dis[sv.w] * dis[cv.w];
    bk = cv.w >> 6; rk = atomicAdd(&lcnt[bk], 1);
    meta[lbase[bk] + rk] = ((u64)__float_as_uint(w) << 32) | ((u32)cv.w << 16) | (u32)sv.w;
  }
}

// ---------------- propagation (bucket-block, LDS fp32 accumulate) ----------------
// Block b owns cols [b*64, b*64+64): acc[64][128] fp32 in LDS (32 KB).
// Per edge: full wave gathers the 256B source row (u32/lane), 2 native
// ds_add_f32 per lane into acc[col&63].  8-edge unroll per wave for MLP.
// Zero-weight padding records make tail handling free (atomicAdd of 0).
__global__ __launch_bounds__(256) void k_prop_lds(const int* __restrict__ excl, const u64* __restrict__ meta,
                                                  const u32* __restrict__ h, const u32* __restrict__ other,
                                                  u32* __restrict__ outb,
                                                  const float coefP, const float coefO) {
  __shared__ float acc[64 * CH];   // 32 KB
  const int b = blockIdx.x, t = threadIdx.x;
  const int lane = t & 63, wid = t >> 6;
  const int seg0 = excl[b * BH];
  const int seg1 = (b + 1 < NBUCK) ? excl[(b + 1) * BH] : NE;
  for (int i = t * 4; i < 64 * CH; i += 1024)
    *(float4*)&acc[i] = make_float4(0.f, 0.f, 0.f, 0.f);
  __syncthreads();

  for (int p0 = seg0 + wid * 8; p0 < seg1; p0 += 32) {
    u64 r[8];
#pragma unroll
    for (int k = 0; k < 8; ++k) {
      int p = p0 + k;
      r[k] = (p < seg1) ? meta[p] : 0ull;    // pad: w=0, col 0, src 0
    }
    u32 v[8];
#pragma unroll
    for (int k = 0; k < 8; ++k)
      v[k] = h[(size_t)((u32)r[k] & 0xFFFFu) * 64 + lane];
#pragma unroll
    for (int k = 0; k < 8; ++k) {
      const float w = __uint_as_float((u32)(r[k] >> 32));
      const int cl = ((u32)r[k] >> 16) & 63;
      float* a = &acc[cl * CH + lane * 2];
      atomicAdd(&a[0], w * bflo(v[k]));
      atomicAdd(&a[1], w * bfhi(v[k]));
    }
  }
  __syncthreads();

  // write out 64 nodes x 256 B (+ coefO*other)
  for (int q = t; q < 64 * 16; q += 256) {
    const int nl = q >> 4, qq = q & 15;
    const int node = (b << 6) + nl;
    if (node >= NN) continue;
    const float* a = &acc[nl * CH + qq * 8];
    const size_t oi = (size_t)node * 64 + qq * 4;
    float o0 = 0.f, o1 = 0.f, o2 = 0.f, o3 = 0.f, o4 = 0.f, o5 = 0.f, o6 = 0.f, o7 = 0.f;
    if (other != nullptr) {
      u32x4 ov = *(const u32x4*)&other[oi];
      o0 = bflo(ov.x); o1 = bfhi(ov.x); o2 = bflo(ov.y); o3 = bfhi(ov.y);
      o4 = bflo(ov.z); o5 = bfhi(ov.z); o6 = bflo(ov.w); o7 = bfhi(ov.w);
    }
    u32x4 rr;
    rr.x = pack_bf2(fmaf(coefP, a[0], coefO * o0), fmaf(coefP, a[1], coefO * o1));
    rr.y = pack_bf2(fmaf(coefP, a[2], coefO * o2), fmaf(coefP, a[3], coefO * o3));
    rr.z = pack_bf2(fmaf(coefP, a[4], coefO * o4), fmaf(coefP, a[5], coefO * o5));
    rr.w = pack_bf2(fmaf(coefP, a[6], coefO * o6), fmaf(coefP, a[7], coefO * o7));
    *(u32x4*)&outb[oi] = rr;
  }
}

// ---------------- fused 4-output MFMA GEMM (streamed basis tiles) ----------------
// 32 rows/block, 4 waves (wave w -> cols w*32..w*32+31).
__global__ __launch_bounds__(256, 4) void k_gemm_all(
    const u16* __restrict__ xb, const u16* __restrict__ t1,
    const u16* __restrict__ t2, const u16* __restrict__ t3,
    const u16* __restrict__ Wp,
    const float* __restrict__ b0, const float* __restrict__ b1,
    const float* __restrict__ b2, const float* __restrict__ b3,
    float* __restrict__ out) {
  __shared__ __align__(16) char ldsb[2][8192];   // 2 x 32 rows x 256 B
  const int tid = threadIdx.x;
  const int w = tid >> 6, lane = tid & 63;
  const int rowg0 = blockIdx.x * 32;
  const u16* bases[4] = {xb, t1, t2, t3};
  const int mbase[4] = {0, 1, 3, 6};

  const int c0 = tid,        r_0 = c0 >> 4, s_0 = (c0 & 15) << 4;
  const int c1 = 256 + tid,  r_1 = c1 >> 4, s_1 = (c1 & 15) << 4;

  f32x4 acc[4][2][2];
#pragma unroll
  for (int k = 0; k < 4; ++k)
#pragma unroll
    for (int rf = 0; rf < 2; ++rf)
#pragma unroll
      for (int c = 0; c < 2; ++c) acc[k][rf][c] = (f32x4){0.f, 0.f, 0.f, 0.f};

  // prologue: stage tile 0
  {
    u16x8 v0 = {0,0,0,0,0,0,0,0}, v1 = {0,0,0,0,0,0,0,0};
    if (rowg0 + r_0 < NN) v0 = *(const u16x8*)((const char*)bases[0] + (size_t)(rowg0 + r_0) * 256 + s_0);
    if (rowg0 + r_1 < NN) v1 = *(const u16x8*)((const char*)bases[0] + (size_t)(rowg0 + r_1) * 256 + s_1);
    *(u16x8*)(&ldsb[0][r_0 * 256 + (s_0 ^ ((r_0 & 7) << 4))]) = v0;
    *(u16x8*)(&ldsb[0][r_1 * 256 + (s_1 ^ ((r_1 & 7) << 4))]) = v1;
  }
  __syncthreads();

#pragma unroll
  for (int i = 0; i < 4; ++i) {
    u16x8 nv0 = {0,0,0,0,0,0,0,0}, nv1 = {0,0,0,0,0,0,0,0};
    if (i < 3) {
      if (rowg0 + r_0 < NN) nv0 = *(const u16x8*)((const char*)bases[i + 1] + (size_t)(rowg0 + r_0) * 256 + s_0);
      if (rowg0 + r_1 < NN) nv1 = *(const u16x8*)((const char*)bases[i + 1] + (size_t)(rowg0 + r_1) * 256 + s_1);
    }

    const char* tile = ldsb[i & 1];
#pragma unroll
    for (int ks = 0; ks < 4; ++ks) {
      const int kb = ks * 64 + ((lane >> 4) << 4);
      const int r0 = (lane & 15), r1 = 16 + (lane & 15);
      const bf16x8 a0 = __builtin_bit_cast(bf16x8,
          *(const u16x8*)(tile + r0 * 256 + (kb ^ ((r0 & 7) << 4))));
      const bf16x8 a1 = __builtin_bit_cast(bf16x8,
          *(const u16x8*)(tile + r1 * 256 + (kb ^ ((r1 & 7) << 4))));
#pragma unroll
      for (int k = 3; k >= 0; --k) {
        if (k < i) continue;
        const int m = mbase[k] + i;
        const bf16x8 bf0 = __builtin_bit_cast(bf16x8,
            *(const u16x8*)(Wp + (size_t)((m * 4 + ks) * 8 + (w * 2 + 0)) * 512 + lane * 8));
        const bf16x8 bf1 = __builtin_bit_cast(bf16x8,
            *(const u16x8*)(Wp + (size_t)((m * 4 + ks) * 8 + (w * 2 + 1)) * 512 + lane * 8));
        acc[k][0][0] = __builtin_amdgcn_mfma_f32_16x16x32_bf16(a0, bf0, acc[k][0][0], 0, 0, 0);
        acc[k][1][0] = __builtin_amdgcn_mfma_f32_16x16x32_bf16(a1, bf0, acc[k][1][0], 0, 0, 0);
        acc[k][0][1] = __builtin_amdgcn_mfma_f32_16x16x32_bf16(a0, bf1, acc[k][0][1], 0, 0, 0);
        acc[k][1][1] = __builtin_amdgcn_mfma_f32_16x16x32_bf16(a1, bf1, acc[k][1][1], 0, 0, 0);
      }
    }
    if (i < 3) {
      char* nb = ldsb[(i + 1) & 1];
      *(u16x8*)(&nb[r_0 * 256 + (s_0 ^ ((r_0 & 7) << 4))]) = nv0;
      *(u16x8*)(&nb[r_1 * 256 + (s_1 ^ ((r_1 & 7) << 4))]) = nv1;
    }
    __syncthreads();
  }

  // epilogue: bias + relu + fp32 store.  C/D: col=lane&15, row=(lane>>4)*4+j
  const float* biases[4] = {b0, b1, b2, b3};
  const int colb = w * 32;
#pragma unroll
  for (int k = 0; k < 4; ++k) {
    const float bv0 = biases[k][colb + (lane & 15)];
    const float bv1 = biases[k][colb + 16 + (lane & 15)];
    float* ok = out + (size_t)k * NN * CH;
#pragma unroll
    for (int rf = 0; rf < 2; ++rf) {
#pragma unroll
      for (int j = 0; j < 4; ++j) {
        const int row = rowg0 + rf * 16 + ((lane >> 4) << 2) + j;
        if (row < NN) {
          ok[(size_t)row * CH + colb + (lane & 15)]      = fmaxf(acc[k][rf][0][j] + bv0, 0.f);
          ok[(size_t)row * CH + colb + 16 + (lane & 15)] = fmaxf(acc[k][rf][1][j] + bv1, 0.f);
        }
      }
    }
  }
}

// ---------------- launch ----------------
static inline size_t align256(size_t x) { return (x + 255) & ~(size_t)255; }

extern "C" void kernel_launch(void* const* d_in, const int* in_sizes, int n_in,
                              void* d_out, int out_size, void* d_ws, size_t ws_size,
                              hipStream_t stream) {
  const float* x  = (const float*)d_in[0];
  const int*   ei = (const int*)d_in[1];
  const float* ew = (const float*)d_in[2];
  const float* W[4]  = {(const float*)d_in[3], (const float*)d_in[5],
                        (const float*)d_in[7], (const float*)d_in[9]};
  const float* bs[4] = {(const float*)d_in[4], (const float*)d_in[6],
                        (const float*)d_in[8], (const float*)d_in[10]};
  float* out = (float*)d_out;

  char* ws = (char*)d_ws;
  size_t off = 0;
  auto alloc = [&](size_t bytes) -> void* { void* p = ws + off; off = align256(off + bytes); return p; };
  float* dis      = (float*)alloc(sizeof(float) * NN);
  int*   hist     = (int*)alloc(sizeof(int) * MH);
  int*   partials = (int*)alloc(sizeof(int) * 4096);
  int*   part     = (int*)alloc(sizeof(int) * (size_t)DC * NN);
  u64*   meta     = (u64*)alloc(sizeof(u64) * NE);
  u32*   xb       = (u32*)alloc(sizeof(u32) * (size_t)NN * 64);
  u32*   t1b      = (u32*)alloc(sizeof(u32) * (size_t)NN * 64);
  u32*   t2b      = (u32*)alloc(sizeof(u32) * (size_t)NN * 64);
  u32*   t3b      = (u32*)alloc(sizeof(u32) * (size_t)NN * 64);
  u16*   Wp       = (u16*)alloc(sizeof(u16) * 10 * 4 * 8 * 64 * 8);
  (void)ws_size; (void)in_sizes; (void)n_in; (void)out_size;

  // front: row-deg + col-hist + conversions (independent, one launch)
  k_front<<<FRONT_BLOCKS, 256, 0, stream>>>(ei, ew, part, hist, x, xb,
                                            W[0], W[1], W[2], W[3], Wp);

  // bucket CSR (no per-col sort needed)
  k_scan1<<<G1, 256, 0, stream>>>(hist, partials);
  k_scan2<<<1, 256, 0, stream>>>(partials);
  k_mid<<<G1 + (NN + 255) / 256, 256, 0, stream>>>(hist, partials, part, dis);
  kC<<<BH, 256, 0, stream>>>(ei, ew, hist, dis, meta);

  // basis: Tx1 = -P(x); Tx2 = -1.5 P(Tx1) - 0.5 x; Tx3 = -(5/3) P(Tx2) - (2/3) Tx1
  k_prop_lds<<<NBUCK, 256, 0, stream>>>(hist, meta, xb, nullptr, t1b, -1.f, 0.f);
  k_prop_lds<<<NBUCK, 256, 0, stream>>>(hist, meta, t1b, xb, t2b, -1.5f, -0.5f);
  k_prop_lds<<<NBUCK, 256, 0, stream>>>(hist, meta, t2b, t1b, t3b, -5.f / 3.f, -2.f / 3.f);

  // fused 4-output GEMM with bias+relu (32-row blocks)
  k_gemm_all<<<(NN + 31) / 32, 256, 0, stream>>>(
      (const u16*)xb, (const u16*)t1b, (const u16*)t2b, (const u16*)t3b,
      Wp, bs[0], bs[1], bs[2], bs[3], out);
}

// Round 13
// 189.038 us; speedup vs baseline: 11.3966x; 11.3966x over previous
//
#include <hip/hip_runtime.h>
#include <cstddef>
#include <cstdint>

#define NN 50000
#define NE 800000
#define CH 128

// counting-sort geometry
#define NBUCK 782                 // ceil(50000/64) buckets of 64 cols
#define BH 200                    // blocks in place kernel
#define EPB 4000                  // edges per place-block (200*4000 = 800000)
#define MH (NBUCK * BH)           // 156400 hist entries
#define G1 ((MH + 255) / 256)     // 611 scan blocks

// deg (row-degree) filtered-histogram geometry
#define DR 8                      // row ranges
#define DRS 6250                  // rows per range (8*6250 = 50000)
#define DC 50                     // edge chunks
#define DCE 16000                 // edges per chunk (50*16000 = 800000)
#define DBLK 448                  // swizzled launch: 7*8*8 (48 blocks idle)

#define FIXS 8388608.0f           // 2^23 fixed-point scale for deg accumulation

typedef unsigned int u32;
typedef unsigned short u16;
typedef unsigned long long u64;
typedef __attribute__((ext_vector_type(4))) unsigned int u32x4;
typedef __attribute__((ext_vector_type(8))) unsigned short u16x8;
typedef __attribute__((ext_vector_type(8))) __bf16 bf16x8;
typedef __attribute__((ext_vector_type(4))) float f32x4;

// ---------------- bf16 helpers ----------------
__device__ __forceinline__ u32 bf_rne(float f) {
  u32 u = __float_as_uint(f);
  return (u + 0x7FFFu + ((u >> 16) & 1u)) >> 16;
}
__device__ __forceinline__ u32 pack_bf2(float lo, float hi) {
  return bf_rne(lo) | (bf_rne(hi) << 16);
}
__device__ __forceinline__ float bflo(u32 v) { return __uint_as_float(v << 16); }
__device__ __forceinline__ float bfhi(u32 v) { return __uint_as_float(v & 0xFFFF0000u); }

// ---------------- scan helpers ----------------
__device__ __forceinline__ int wave_scan_incl(int v) {
  int lane = threadIdx.x & 63;
#pragma unroll
  for (int d = 1; d < 64; d <<= 1) {
    int u = __shfl_up(v, d, 64);
    if (lane >= d) v += u;
  }
  return v;
}

__device__ __forceinline__ int block_scan_incl(int v, int* wsum) {
  int t = threadIdx.x, lane = t & 63, wid = t >> 6;
  int incl = wave_scan_incl(v);
  if (lane == 63) wsum[wid] = incl;
  __syncthreads();
  int add = 0;
#pragma unroll
  for (int w = 0; w < 3; ++w) add += (w < wid) ? wsum[w] : 0;
  return incl + add;
}

// ---------------- row degree + col-bucket hist (vec4 loads, XCD-swizzled) ----------------
// Chunk c's 8 row-range blocks all share blockIdx%8 == c%8 -> same XCD under
// round-robin dispatch -> 7/8 redundant chunk reads hit that XCD's 4MB L2.
__global__ __launch_bounds__(256) void kB_deg(const int* __restrict__ ei, const float* __restrict__ ew,
                                              int* __restrict__ part, int* __restrict__ hist) {
  __shared__ u32 lh[DRS];
  __shared__ int ch[NBUCK];
  const int bid = blockIdx.x;
  const int low3 = bid & 7;
  const int q = bid >> 3;          // 0..55
  const int r = q & 7;
  const int chi = q >> 3;          // 0..6
  const int c = chi * 8 + low3;    // 0..55
  if (c >= DC) return;
  const int t = threadIdx.x;
  for (int i = t; i < DRS; i += 256) lh[i] = 0u;
  if (r < 4) for (int i = t; i < NBUCK; i += 256) ch[i] = 0;
  __syncthreads();
  const int base = r * DRS;
  const int4* rows4 = (const int4*)(ei + c * DCE);
  const float4* ws4 = (const float4*)(ew + c * DCE);
  for (int v = t; v < DCE / 4; v += 256) {
    int4 rv = rows4[v];
    float4 wv = ws4[v];
    unsigned rel;
    rel = (unsigned)(rv.x - base); if (rel < (unsigned)DRS) atomicAdd(&lh[rel], (u32)(wv.x * FIXS + 0.5f));
    rel = (unsigned)(rv.y - base); if (rel < (unsigned)DRS) atomicAdd(&lh[rel], (u32)(wv.y * FIXS + 0.5f));
    rel = (unsigned)(rv.z - base); if (rel < (unsigned)DRS) atomicAdd(&lh[rel], (u32)(wv.z * FIXS + 0.5f));
    rel = (unsigned)(rv.w - base); if (rel < (unsigned)DRS) atomicAdd(&lh[rel], (u32)(wv.w * FIXS + 0.5f));
  }
  if (r < 4) {
    const int cb = 4 * c + r;                // kC sub-chunk 0..199
    const int4* cols4 = (const int4*)(ei + NE + cb * EPB);
    for (int v = t; v < EPB / 4; v += 256) {
      int4 cv = cols4[v];
      atomicAdd(&ch[cv.x >> 6], 1);
      atomicAdd(&ch[cv.y >> 6], 1);
      atomicAdd(&ch[cv.z >> 6], 1);
      atomicAdd(&ch[cv.w >> 6], 1);
    }
  }
  __syncthreads();
  int* dst = part + (size_t)c * NN + base;
  for (int i = t; i < DRS; i += 256) dst[i] = (int)lh[i];
  if (r < 4) {
    const int cb = 4 * c + r;
    for (int i = t; i < NBUCK; i += 256) hist[i * BH + cb] = ch[i];
  }
}

__global__ __launch_bounds__(256) void k_degred(const int* __restrict__ part, float* __restrict__ dis) {
  int i = blockIdx.x * 256 + threadIdx.x;
  if (i >= NN) return;
  int s = 0;
#pragma unroll 10
  for (int c = 0; c < DC; ++c) s += part[(size_t)c * NN + i];
  dis[i] = (s > 0) ? rsqrtf((float)s * (1.0f / FIXS)) : 0.f;
}

__global__ __launch_bounds__(256) void k_scan1(const int* __restrict__ hist, int* __restrict__ partials) {
  __shared__ int wsum[4];
  int i = blockIdx.x * 256 + threadIdx.x;
  int v = (i < MH) ? hist[i] : 0;
  int incl = block_scan_incl(v, wsum);
  if (threadIdx.x == 255) partials[blockIdx.x] = incl;
}

__global__ __launch_bounds__(256) void k_scan2(int* __restrict__ partials) {
  __shared__ int wsum[4];
  __shared__ int carrys;
  const int t = threadIdx.x;
  int carry = 0;
#pragma unroll
  for (int r = 0; r < 3; ++r) {
    int idx = r * 256 + t;
    int v = (idx < G1) ? partials[idx] : 0;
    int incl = block_scan_incl(v, wsum);
    if (idx < G1) partials[idx] = carry + incl - v;   // exclusive
    if (t == 255) carrys = incl;
    __syncthreads();
    carry += carrys;
    __syncthreads();
  }
}

__global__ __launch_bounds__(256) void k_scan3(int* __restrict__ hist, const int* __restrict__ partials) {
  __shared__ int wsum[4];
  int i = blockIdx.x * 256 + threadIdx.x;
  int v = (i < MH) ? hist[i] : 0;
  int incl = block_scan_incl(v, wsum);
  if (i < MH) hist[i] = incl - v + partials[blockIdx.x];   // exclusive, in place
}

__global__ __launch_bounds__(256) void kC(const int* __restrict__ ei, const float* __restrict__ ew,
                                          const int* __restrict__ excl, u64* __restrict__ sorted) {
  __shared__ int lbase[NBUCK];
  __shared__ int lcnt[NBUCK];
  const int b = blockIdx.x, t = threadIdx.x;
  for (int i = t; i < NBUCK; i += 256) { lbase[i] = excl[i * BH + b]; lcnt[i] = 0; }
  __syncthreads();
  const int e0 = b * EPB;
  const int4* srcs4 = (const int4*)(ei + e0);
  const int4* cols4 = (const int4*)(ei + NE + e0);
  const float4* ws4 = (const float4*)(ew + e0);
  for (int v = t; v < EPB / 4; v += 256) {
    int4 sv = srcs4[v];
    int4 cv = cols4[v];
    float4 wv = ws4[v];
    int bk, rk;
    bk = cv.x >> 6; rk = atomicAdd(&lcnt[bk], 1);
    sorted[lbase[bk] + rk] = ((u64)__float_as_uint(wv.x) << 32) | ((u32)cv.x << 16) | (u32)sv.x;
    bk = cv.y >> 6; rk = atomicAdd(&lcnt[bk], 1);
    sorted[lbase[bk] + rk] = ((u64)__float_as_uint(wv.y) << 32) | ((u32)cv.y << 16) | (u32)sv.y;
    bk = cv.z >> 6; rk = atomicAdd(&lcnt[bk], 1);
    sorted[lbase[bk] + rk] = ((u64)__float_as_uint(wv.z) << 32) | ((u32)cv.z << 16) | (u32)sv.z;
    bk = cv.w >> 6; rk = atomicAdd(&lcnt[bk], 1);
    sorted[lbase[bk] + rk] = ((u64)__float_as_uint(wv.w) << 32) | ((u32)cv.w << 16) | (u32)sv.w;
  }
}

// per-bucket counting sort -> CSR (rp, packed meta {w:f32,src:u16})
__global__ __launch_bounds__(256) void kD(const u64* __restrict__ sorted, const int* __restrict__ excl,
                                          const float* __restrict__ dis, int* __restrict__ rp,
                                          u64* __restrict__ meta) {
  __shared__ int h[64];
  __shared__ int cur[64];
  __shared__ float disc[64];
  const int b = blockIdx.x, t = threadIdx.x;
  const int seg0 = excl[b * BH];
  const int seg1 = (b + 1 < NBUCK) ? excl[(b + 1) * BH] : NE;
  if (t < 64) {
    h[t] = 0;
    int c = (b << 6) + t;
    disc[t] = (c < NN) ? dis[c] : 0.f;
  }
  __syncthreads();
  for (int p = seg0 + t; p < seg1; p += 256) {
    u32 lo = (u32)sorted[p];
    atomicAdd(&h[(lo >> 16) & 63], 1);
  }
  __syncthreads();
  if (t < 64) {
    int v = h[t];
    int incl = wave_scan_incl(v);
    int excl_l = incl - v;
    cur[t] = seg0 + excl_l;
    int c = (b << 6) + t;
    if (c < NN) rp[c] = seg0 + excl_l;
    else if (c == NN) rp[NN] = seg0 + excl_l;   // == NE
  }
  __syncthreads();
  for (int p = seg0 + t; p < seg1; p += 256) {
    u64 v = sorted[p];
    u32 lo = (u32)v;
    int src = lo & 0xFFFF;
    int local = (lo >> 16) & 63;
    float ewf = __uint_as_float((u32)(v >> 32));
    int q = atomicAdd(&cur[local], 1);
    float w = ewf * dis[src] * disc[local];
    meta[q] = ((u64)__float_as_uint(w) << 32) | (u32)src;
  }
}

// ---------------- conversions (x2bf + wpack fused) ----------------
#define XB_BLOCKS 12500           // NN*64 pairs / 256
__global__ __launch_bounds__(256) void k_conv(const float* __restrict__ x, u32* __restrict__ xb,
                                              const float* __restrict__ W0, const float* __restrict__ W1,
                                              const float* __restrict__ W2, const float* __restrict__ W3,
                                              u16* __restrict__ Wp) {
  if (blockIdx.x < XB_BLOCKS) {
    int i = blockIdx.x * 256 + threadIdx.x;     // pairs
    if (i < NN * 64) {
      float2 f = ((const float2*)x)[i];
      xb[i] = pack_bf2(f.x, f.y);
    }
    return;
  }
  int t = (blockIdx.x - XB_BLOCKS) * 256 + threadIdx.x;
  if (t >= 10 * 4 * 8 * 64) return;
  int lane = t & 63, cb = (t >> 6) & 7, kb = (t >> 9) & 3, m = t >> 11;
  const float* Wb; int io;
  if (m == 0)      { Wb = W0; io = 0; }
  else if (m < 3)  { Wb = W1; io = m - 1; }
  else if (m < 6)  { Wb = W2; io = m - 3; }
  else             { Wb = W3; io = m - 6; }
  const float* s = Wb + (size_t)io * CH * CH;
  int c  = cb * 16 + (lane & 15);
  int k0 = kb * 32 + (lane >> 4) * 8;
  u16* o = Wp + (size_t)t * 8;
#pragma unroll
  for (int e = 0; e < 8; ++e) o[e] = (u16)bf_rne(s[(k0 + e) * CH + c]);
}

// ---------------- propagation (grouped dwordx4 gather, meta software-pipelined) ----------------
__global__ __launch_bounds__(256) void k_prop_bf(const int* __restrict__ rp, const u64* __restrict__ meta,
                                                 const u32* __restrict__ h, const u32* __restrict__ other,
                                                 u32* __restrict__ outb,
                                                 const float coefP, const float coefO) {
  const int node = blockIdx.x * 4 + (threadIdx.x >> 6);
  const int lane = threadIdx.x & 63;
  const int g = lane >> 4;          // edge group 0..3
  const int cq = lane & 15;         // u32-quad index within row
  if (node >= NN) return;
  const int j0 = rp[node], j1 = rp[node + 1];
  float a0 = 0.f, a1 = 0.f, a2 = 0.f, a3 = 0.f, a4 = 0.f, a5 = 0.f, a6 = 0.f, a7 = 0.f;
  if (j0 < j1) {
    int ji = j0 + g;
    u64 mnext = meta[(ji < j1) ? ji : (j1 - 1)];
#pragma unroll 4
    for (int j = j0; j < j1; j += 4) {
      const u64 m = mnext;
      const int jn = j + 4 + g;
      mnext = meta[(jn < j1) ? jn : (j1 - 1)];            // prefetch next stage
      const bool act = (j + g) < j1;
      const float w = act ? __uint_as_float((u32)(m >> 32)) : 0.f;
      const u32 src = (u32)m & 0xFFFFu;
      u32x4 v = *(const u32x4*)&h[(size_t)src * 64 + cq * 4];
      a0 = fmaf(w, bflo(v.x), a0); a1 = fmaf(w, bfhi(v.x), a1);
      a2 = fmaf(w, bflo(v.y), a2); a3 = fmaf(w, bfhi(v.y), a3);
      a4 = fmaf(w, bflo(v.z), a4); a5 = fmaf(w, bfhi(v.z), a5);
      a6 = fmaf(w, bflo(v.w), a6); a7 = fmaf(w, bfhi(v.w), a7);
    }
  }
  // reduce across the 4 edge groups
  a0 += __shfl_xor(a0, 16); a1 += __shfl_xor(a1, 16);
  a2 += __shfl_xor(a2, 16); a3 += __shfl_xor(a3, 16);
  a4 += __shfl_xor(a4, 16); a5 += __shfl_xor(a5, 16);
  a6 += __shfl_xor(a6, 16); a7 += __shfl_xor(a7, 16);
  a0 += __shfl_xor(a0, 32); a1 += __shfl_xor(a1, 32);
  a2 += __shfl_xor(a2, 32); a3 += __shfl_xor(a3, 32);
  a4 += __shfl_xor(a4, 32); a5 += __shfl_xor(a5, 32);
  a6 += __shfl_xor(a6, 32); a7 += __shfl_xor(a7, 32);
  if (lane < 16) {
    const size_t oi = (size_t)node * 64 + cq * 4;
    float o0 = 0.f, o1 = 0.f, o2 = 0.f, o3 = 0.f, o4 = 0.f, o5 = 0.f, o6 = 0.f, o7 = 0.f;
    if (other != nullptr) {
      u32x4 ov = *(const u32x4*)&other[oi];
      o0 = bflo(ov.x); o1 = bfhi(ov.x); o2 = bflo(ov.y); o3 = bfhi(ov.y);
      o4 = bflo(ov.z); o5 = bfhi(ov.z); o6 = bflo(ov.w); o7 = bfhi(ov.w);
    }
    u32x4 r;
    r.x = pack_bf2(fmaf(coefP, a0, coefO * o0), fmaf(coefP, a1, coefO * o1));
    r.y = pack_bf2(fmaf(coefP, a2, coefO * o2), fmaf(coefP, a3, coefO * o3));
    r.z = pack_bf2(fmaf(coefP, a4, coefO * o4), fmaf(coefP, a5, coefO * o5));
    r.w = pack_bf2(fmaf(coefP, a6, coefO * o6), fmaf(coefP, a7, coefO * o7));
    *(u32x4*)&outb[oi] = r;
  }
}

// ---------------- fused 4-output MFMA GEMM (streamed basis tiles) ----------------
// 32 rows/block, 4 waves (wave w -> cols w*32..w*32+31).
__global__ __launch_bounds__(256, 4) void k_gemm_all(
    const u16* __restrict__ xb, const u16* __restrict__ t1,
    const u16* __restrict__ t2, const u16* __restrict__ t3,
    const u16* __restrict__ Wp,
    const float* __restrict__ b0, const float* __restrict__ b1,
    const float* __restrict__ b2, const float* __restrict__ b3,
    float* __restrict__ out) {
  __shared__ __align__(16) char ldsb[2][8192];   // 2 x 32 rows x 256 B
  const int tid = threadIdx.x;
  const int w = tid >> 6, lane = tid & 63;
  const int rowg0 = blockIdx.x * 32;
  const u16* bases[4] = {xb, t1, t2, t3};
  const int mbase[4] = {0, 1, 3, 6};

  const int c0 = tid,        r_0 = c0 >> 4, s_0 = (c0 & 15) << 4;
  const int c1 = 256 + tid,  r_1 = c1 >> 4, s_1 = (c1 & 15) << 4;

  f32x4 acc[4][2][2];
#pragma unroll
  for (int k = 0; k < 4; ++k)
#pragma unroll
    for (int rf = 0; rf < 2; ++rf)
#pragma unroll
      for (int c = 0; c < 2; ++c) acc[k][rf][c] = (f32x4){0.f, 0.f, 0.f, 0.f};

  // prologue: stage tile 0
  {
    u16x8 v0 = {0,0,0,0,0,0,0,0}, v1 = {0,0,0,0,0,0,0,0};
    if (rowg0 + r_0 < NN) v0 = *(const u16x8*)((const char*)bases[0] + (size_t)(rowg0 + r_0) * 256 + s_0);
    if (rowg0 + r_1 < NN) v1 = *(const u16x8*)((const char*)bases[0] + (size_t)(rowg0 + r_1) * 256 + s_1);
    *(u16x8*)(&ldsb[0][r_0 * 256 + (s_0 ^ ((r_0 & 7) << 4))]) = v0;
    *(u16x8*)(&ldsb[0][r_1 * 256 + (s_1 ^ ((r_1 & 7) << 4))]) = v1;
  }
  __syncthreads();

#pragma unroll
  for (int i = 0; i < 4; ++i) {
    u16x8 nv0 = {0,0,0,0,0,0,0,0}, nv1 = {0,0,0,0,0,0,0,0};
    if (i < 3) {
      if (rowg0 + r_0 < NN) nv0 = *(const u16x8*)((const char*)bases[i + 1] + (size_t)(rowg0 + r_0) * 256 + s_0);
      if (rowg0 + r_1 < NN) nv1 = *(const u16x8*)((const char*)bases[i + 1] + (size_t)(rowg0 + r_1) * 256 + s_1);
    }

    const char* tile = ldsb[i & 1];
#pragma unroll
    for (int ks = 0; ks < 4; ++ks) {
      const int kb = ks * 64 + ((lane >> 4) << 4);
      const int r0 = (lane & 15), r1 = 16 + (lane & 15);
      const bf16x8 a0 = __builtin_bit_cast(bf16x8,
          *(const u16x8*)(tile + r0 * 256 + (kb ^ ((r0 & 7) << 4))));
      const bf16x8 a1 = __builtin_bit_cast(bf16x8,
          *(const u16x8*)(tile + r1 * 256 + (kb ^ ((r1 & 7) << 4))));
#pragma unroll
      for (int k = 3; k >= 0; --k) {
        if (k < i) continue;
        const int m = mbase[k] + i;
        const bf16x8 bf0 = __builtin_bit_cast(bf16x8,
            *(const u16x8*)(Wp + (size_t)((m * 4 + ks) * 8 + (w * 2 + 0)) * 512 + lane * 8));
        const bf16x8 bf1 = __builtin_bit_cast(bf16x8,
            *(const u16x8*)(Wp + (size_t)((m * 4 + ks) * 8 + (w * 2 + 1)) * 512 + lane * 8));
        acc[k][0][0] = __builtin_amdgcn_mfma_f32_16x16x32_bf16(a0, bf0, acc[k][0][0], 0, 0, 0);
        acc[k][1][0] = __builtin_amdgcn_mfma_f32_16x16x32_bf16(a1, bf0, acc[k][1][0], 0, 0, 0);
        acc[k][0][1] = __builtin_amdgcn_mfma_f32_16x16x32_bf16(a0, bf1, acc[k][0][1], 0, 0, 0);
        acc[k][1][1] = __builtin_amdgcn_mfma_f32_16x16x32_bf16(a1, bf1, acc[k][1][1], 0, 0, 0);
      }
    }
    if (i < 3) {
      char* nb = ldsb[(i + 1) & 1];
      *(u16x8*)(&nb[r_0 * 256 + (s_0 ^ ((r_0 & 7) << 4))]) = nv0;
      *(u16x8*)(&nb[r_1 * 256 + (s_1 ^ ((r_1 & 7) << 4))]) = nv1;
    }
    __syncthreads();
  }

  // epilogue: bias + relu + fp32 store.  C/D: col=lane&15, row=(lane>>4)*4+j
  const float* biases[4] = {b0, b1, b2, b3};
  const int colb = w * 32;
#pragma unroll
  for (int k = 0; k < 4; ++k) {
    const float bv0 = biases[k][colb + (lane & 15)];
    const float bv1 = biases[k][colb + 16 + (lane & 15)];
    float* ok = out + (size_t)k * NN * CH;
#pragma unroll
    for (int rf = 0; rf < 2; ++rf) {
#pragma unroll
      for (int j = 0; j < 4; ++j) {
        const int row = rowg0 + rf * 16 + ((lane >> 4) << 2) + j;
        if (row < NN) {
          ok[(size_t)row * CH + colb + (lane & 15)]      = fmaxf(acc[k][rf][0][j] + bv0, 0.f);
          ok[(size_t)row * CH + colb + 16 + (lane & 15)] = fmaxf(acc[k][rf][1][j] + bv1, 0.f);
        }
      }
    }
  }
}

// ---------------- launch ----------------
static inline size_t align256(size_t x) { return (x + 255) & ~(size_t)255; }

extern "C" void kernel_launch(void* const* d_in, const int* in_sizes, int n_in,
                              void* d_out, int out_size, void* d_ws, size_t ws_size,
                              hipStream_t stream) {
  const float* x  = (const float*)d_in[0];
  const int*   ei = (const int*)d_in[1];
  const float* ew = (const float*)d_in[2];
  const float* W[4]  = {(const float*)d_in[3], (const float*)d_in[5],
                        (const float*)d_in[7], (const float*)d_in[9]};
  const float* bs[4] = {(const float*)d_in[4], (const float*)d_in[6],
                        (const float*)d_in[8], (const float*)d_in[10]};
  float* out = (float*)d_out;

  char* ws = (char*)d_ws;
  size_t off = 0;
  auto alloc = [&](size_t bytes) -> void* { void* p = ws + off; off = align256(off + bytes); return p; };
  float* dis      = (float*)alloc(sizeof(float) * NN);
  int*   rp       = (int*)alloc(sizeof(int) * (NN + 1));
  int*   hist     = (int*)alloc(sizeof(int) * MH);
  int*   partials = (int*)alloc(sizeof(int) * 1024);
  int*   part     = (int*)alloc(sizeof(int) * (size_t)DC * NN);
  u64*   sorted   = (u64*)alloc(sizeof(u64) * NE);
  u64*   meta     = (u64*)alloc(sizeof(u64) * NE);
  u32*   xb       = (u32*)alloc(sizeof(u32) * (size_t)NN * 64);
  u32*   t1b      = (u32*)alloc(sizeof(u32) * (size_t)NN * 64);
  u32*   t2b      = (u32*)alloc(sizeof(u32) * (size_t)NN * 64);
  u32*   t3b      = (u32*)alloc(sizeof(u32) * (size_t)NN * 64);
  u16*   Wp       = (u16*)alloc(sizeof(u16) * 10 * 4 * 8 * 64 * 8);
  (void)ws_size; (void)in_sizes; (void)n_in; (void)out_size;

  // row degree (vec4, XCD-swizzled) + col-bucket hist
  kB_deg<<<DBLK, 256, 0, stream>>>(ei, ew, part, hist);
  k_degred<<<(NN + 255) / 256, 256, 0, stream>>>(part, dis);

  // CSR build (counting sort)
  k_scan1<<<G1, 256, 0, stream>>>(hist, partials);
  k_scan2<<<1, 256, 0, stream>>>(partials);
  k_scan3<<<G1, 256, 0, stream>>>(hist, partials);
  kC<<<BH, 256, 0, stream>>>(ei, ew, hist, sorted);
  kD<<<NBUCK, 256, 0, stream>>>(sorted, hist, dis, rp, meta);

  // conversions (x2bf + wpack fused)
  k_conv<<<XB_BLOCKS + 80, 256, 0, stream>>>(x, xb, W[0], W[1], W[2], W[3], Wp);

  // basis: Tx1 = -P(x); Tx2 = -1.5 P(Tx1) - 0.5 x; Tx3 = -(5/3) P(Tx2) - (2/3) Tx1
  k_prop_bf<<<12500, 256, 0, stream>>>(rp, meta, xb, nullptr, t1b, -1.f, 0.f);
  k_prop_bf<<<12500, 256, 0, stream>>>(rp, meta, t1b, xb, t2b, -1.5f, -0.5f);
  k_prop_bf<<<12500, 256, 0, stream>>>(rp, meta, t2b, t1b, t3b, -5.f / 3.f, -2.f / 3.f);

  // fused 4-output GEMM with bias+relu (32-row blocks)
  k_gemm_all<<<(NN + 31) / 32, 256, 0, stream>>>(
      (const u16*)xb, (const u16*)t1b, (const u16*)t2b, (const u16*)t3b,
      Wp, bs[0], bs[1], bs[2], bs[3], out);
}

// Round 14
// 180.499 us; speedup vs baseline: 11.9357x; 1.0473x over previous
//
#include <hip/hip_runtime.h>
#include <cstddef>
#include <cstdint>

#define NN 50000
#define NE 800000
#define CH 128

// counting-sort geometry
#define NBUCK 782                 // ceil(50000/64) buckets of 64 cols
#define BH 200                    // blocks in place kernel
#define EPB 4000                  // edges per place-block (200*4000 = 800000)
#define MH (NBUCK * BH)           // 156400 hist entries
#define G1 ((MH + 255) / 256)     // 611 scan blocks

// deg (row-degree) filtered-histogram geometry
#define DR 8                      // row ranges
#define DRS 6250                  // rows per range (8*6250 = 50000)
#define DC 50                     // edge chunks
#define DCE 16000                 // edges per chunk (50*16000 = 800000)
#define DBLK 448                  // swizzled launch: 7*8*8 (48 blocks idle)

#define FIXS 8388608.0f           // 2^23 fixed-point scale for deg accumulation

#define XB_BLOCKS 12500           // NN*64 pairs / 256
#define CONV_BLOCKS (XB_BLOCKS + 80)
#define FRONT_BLOCKS (DBLK + CONV_BLOCKS)
#define DEGRED_BLOCKS ((NN + 255) / 256)

typedef unsigned int u32;
typedef unsigned short u16;
typedef unsigned long long u64;
typedef __attribute__((ext_vector_type(4))) unsigned int u32x4;
typedef __attribute__((ext_vector_type(8))) unsigned short u16x8;
typedef __attribute__((ext_vector_type(8))) __bf16 bf16x8;
typedef __attribute__((ext_vector_type(4))) float f32x4;

// ---------------- bf16 helpers ----------------
__device__ __forceinline__ u32 bf_rne(float f) {
  u32 u = __float_as_uint(f);
  return (u + 0x7FFFu + ((u >> 16) & 1u)) >> 16;
}
__device__ __forceinline__ u32 pack_bf2(float lo, float hi) {
  return bf_rne(lo) | (bf_rne(hi) << 16);
}
__device__ __forceinline__ float bflo(u32 v) { return __uint_as_float(v << 16); }
__device__ __forceinline__ float bfhi(u32 v) { return __uint_as_float(v & 0xFFFF0000u); }

// ---------------- scan helpers ----------------
__device__ __forceinline__ int wave_scan_incl(int v) {
  int lane = threadIdx.x & 63;
#pragma unroll
  for (int d = 1; d < 64; d <<= 1) {
    int u = __shfl_up(v, d, 64);
    if (lane >= d) v += u;
  }
  return v;
}

__device__ __forceinline__ int block_scan_incl(int v, int* wsum) {
  int t = threadIdx.x, lane = t & 63, wid = t >> 6;
  int incl = wave_scan_incl(v);
  if (lane == 63) wsum[wid] = incl;
  __syncthreads();
  int add = 0;
#pragma unroll
  for (int w = 0; w < 3; ++w) add += (w < wid) ? wsum[w] : 0;
  return incl + add;
}

// ---------------- k_front: row-deg + col-hist ([0,DBLK)) + conversions (rest) ----------------
// deg part identical to R13 kB_deg (vec4 loads, XCD-swizzled, fixed-point LDS);
// conv blocks (independent work) fill CUs that would otherwise idle.
__global__ __launch_bounds__(256) void k_front(const int* __restrict__ ei, const float* __restrict__ ew,
                                               int* __restrict__ part, int* __restrict__ hist,
                                               const float* __restrict__ x, u32* __restrict__ xb,
                                               const float* __restrict__ W0, const float* __restrict__ W1,
                                               const float* __restrict__ W2, const float* __restrict__ W3,
                                               u16* __restrict__ Wp) {
  __shared__ u32 lh[DRS];
  __shared__ int ch[NBUCK];
  const int bid = blockIdx.x;
  const int t = threadIdx.x;

  if (bid < DBLK) {
    const int low3 = bid & 7;
    const int q = bid >> 3;          // 0..55
    const int r = q & 7;
    const int chi = q >> 3;          // 0..6
    const int c = chi * 8 + low3;    // 0..55
    if (c >= DC) return;
    for (int i = t; i < DRS; i += 256) lh[i] = 0u;
    if (r < 4) for (int i = t; i < NBUCK; i += 256) ch[i] = 0;
    __syncthreads();
    const int base = r * DRS;
    const int4* rows4 = (const int4*)(ei + c * DCE);
    const float4* ws4 = (const float4*)(ew + c * DCE);
    for (int v = t; v < DCE / 4; v += 256) {
      int4 rv = rows4[v];
      float4 wv = ws4[v];
      unsigned rel;
      rel = (unsigned)(rv.x - base); if (rel < (unsigned)DRS) atomicAdd(&lh[rel], (u32)(wv.x * FIXS + 0.5f));
      rel = (unsigned)(rv.y - base); if (rel < (unsigned)DRS) atomicAdd(&lh[rel], (u32)(wv.y * FIXS + 0.5f));
      rel = (unsigned)(rv.z - base); if (rel < (unsigned)DRS) atomicAdd(&lh[rel], (u32)(wv.z * FIXS + 0.5f));
      rel = (unsigned)(rv.w - base); if (rel < (unsigned)DRS) atomicAdd(&lh[rel], (u32)(wv.w * FIXS + 0.5f));
    }
    if (r < 4) {
      const int cb = 4 * c + r;                // kC sub-chunk 0..199
      const int4* cols4 = (const int4*)(ei + NE + cb * EPB);
      for (int v = t; v < EPB / 4; v += 256) {
        int4 cv = cols4[v];
        atomicAdd(&ch[cv.x >> 6], 1);
        atomicAdd(&ch[cv.y >> 6], 1);
        atomicAdd(&ch[cv.z >> 6], 1);
        atomicAdd(&ch[cv.w >> 6], 1);
      }
    }
    __syncthreads();
    int* dst = part + (size_t)c * NN + base;
    for (int i = t; i < DRS; i += 256) dst[i] = (int)lh[i];
    if (r < 4) {
      const int cb = 4 * c + r;
      for (int i = t; i < NBUCK; i += 256) hist[i * BH + cb] = ch[i];
    }
    return;
  }

  const int c2 = bid - DBLK;
  if (c2 < XB_BLOCKS) {
    // ---- x -> bf16 pairs ----
    int i = c2 * 256 + t;
    if (i < NN * 64) {
      float2 f = ((const float2*)x)[i];
      xb[i] = pack_bf2(f.x, f.y);
    }
    return;
  }
  // ---- weight pack (MFMA B-fragment layout) ----
  int tt = (c2 - XB_BLOCKS) * 256 + t;
  if (tt >= 10 * 4 * 8 * 64) return;
  int lane = tt & 63, cb = (tt >> 6) & 7, kb = (tt >> 9) & 3, m = tt >> 11;
  const float* Wb; int io;
  if (m == 0)      { Wb = W0; io = 0; }
  else if (m < 3)  { Wb = W1; io = m - 1; }
  else if (m < 6)  { Wb = W2; io = m - 3; }
  else             { Wb = W3; io = m - 6; }
  const float* s = Wb + (size_t)io * CH * CH;
  int c  = cb * 16 + (lane & 15);
  int k0 = kb * 32 + (lane >> 4) * 8;
  u16* o = Wp + (size_t)tt * 8;
#pragma unroll
  for (int e = 0; e < 8; ++e) o[e] = (u16)bf_rne(s[(k0 + e) * CH + c]);
}

// k_scan1d: scan1 (blocks [0,G1)) + degred (blocks [G1, G1+DEGRED_BLOCKS))
__global__ __launch_bounds__(256) void k_scan1d(const int* __restrict__ hist, int* __restrict__ partials,
                                                const int* __restrict__ part, float* __restrict__ dis) {
  __shared__ int wsum[4];
  const int bid = blockIdx.x;
  if (bid < G1) {
    int i = bid * 256 + threadIdx.x;
    int v = (i < MH) ? hist[i] : 0;
    int incl = block_scan_incl(v, wsum);
    if (threadIdx.x == 255) partials[bid] = incl;
    return;
  }
  int i = (bid - G1) * 256 + threadIdx.x;
  if (i >= NN) return;
  int s = 0;
#pragma unroll 10
  for (int c = 0; c < DC; ++c) s += part[(size_t)c * NN + i];
  dis[i] = (s > 0) ? rsqrtf((float)s * (1.0f / FIXS)) : 0.f;
}

__global__ __launch_bounds__(256) void k_scan2(int* __restrict__ partials) {
  __shared__ int wsum[4];
  __shared__ int carrys;
  const int t = threadIdx.x;
  int carry = 0;
#pragma unroll
  for (int r = 0; r < 3; ++r) {
    int idx = r * 256 + t;
    int v = (idx < G1) ? partials[idx] : 0;
    int incl = block_scan_incl(v, wsum);
    if (idx < G1) partials[idx] = carry + incl - v;   // exclusive
    if (t == 255) carrys = incl;
    __syncthreads();
    carry += carrys;
    __syncthreads();
  }
}

__global__ __launch_bounds__(256) void k_scan3(int* __restrict__ hist, const int* __restrict__ partials) {
  __shared__ int wsum[4];
  int i = blockIdx.x * 256 + threadIdx.x;
  int v = (i < MH) ? hist[i] : 0;
  int incl = block_scan_incl(v, wsum);
  if (i < MH) hist[i] = incl - v + partials[blockIdx.x];   // exclusive, in place
}

__global__ __launch_bounds__(256) void kC(const int* __restrict__ ei, const float* __restrict__ ew,
                                          const int* __restrict__ excl, u64* __restrict__ sorted) {
  __shared__ int lbase[NBUCK];
  __shared__ int lcnt[NBUCK];
  const int b = blockIdx.x, t = threadIdx.x;
  for (int i = t; i < NBUCK; i += 256) { lbase[i] = excl[i * BH + b]; lcnt[i] = 0; }
  __syncthreads();
  const int e0 = b * EPB;
  const int4* srcs4 = (const int4*)(ei + e0);
  const int4* cols4 = (const int4*)(ei + NE + e0);
  const float4* ws4 = (const float4*)(ew + e0);
  for (int v = t; v < EPB / 4; v += 256) {
    int4 sv = srcs4[v];
    int4 cv = cols4[v];
    float4 wv = ws4[v];
    int bk, rk;
    bk = cv.x >> 6; rk = atomicAdd(&lcnt[bk], 1);
    sorted[lbase[bk] + rk] = ((u64)__float_as_uint(wv.x) << 32) | ((u32)cv.x << 16) | (u32)sv.x;
    bk = cv.y >> 6; rk = atomicAdd(&lcnt[bk], 1);
    sorted[lbase[bk] + rk] = ((u64)__float_as_uint(wv.y) << 32) | ((u32)cv.y << 16) | (u32)sv.y;
    bk = cv.z >> 6; rk = atomicAdd(&lcnt[bk], 1);
    sorted[lbase[bk] + rk] = ((u64)__float_as_uint(wv.z) << 32) | ((u32)cv.z << 16) | (u32)sv.z;
    bk = cv.w >> 6; rk = atomicAdd(&lcnt[bk], 1);
    sorted[lbase[bk] + rk] = ((u64)__float_as_uint(wv.w) << 32) | ((u32)cv.w << 16) | (u32)sv.w;
  }
}

// per-bucket counting sort -> CSR (rp, packed meta {w:f32,src:u16})
__global__ __launch_bounds__(256) void kD(const u64* __restrict__ sorted, const int* __restrict__ excl,
                                          const float* __restrict__ dis, int* __restrict__ rp,
                                          u64* __restrict__ meta) {
  __shared__ int h[64];
  __shared__ int cur[64];
  __shared__ float disc[64];
  const int b = blockIdx.x, t = threadIdx.x;
  const int seg0 = excl[b * BH];
  const int seg1 = (b + 1 < NBUCK) ? excl[(b + 1) * BH] : NE;
  if (t < 64) {
    h[t] = 0;
    int c = (b << 6) + t;
    disc[t] = (c < NN) ? dis[c] : 0.f;
  }
  __syncthreads();
  for (int p = seg0 + t; p < seg1; p += 256) {
    u32 lo = (u32)sorted[p];
    atomicAdd(&h[(lo >> 16) & 63], 1);
  }
  __syncthreads();
  if (t < 64) {
    int v = h[t];
    int incl = wave_scan_incl(v);
    int excl_l = incl - v;
    cur[t] = seg0 + excl_l;
    int c = (b << 6) + t;
    if (c < NN) rp[c] = seg0 + excl_l;
    else if (c == NN) rp[NN] = seg0 + excl_l;   // == NE
  }
  __syncthreads();
  for (int p = seg0 + t; p < seg1; p += 256) {
    u64 v = sorted[p];
    u32 lo = (u32)v;
    int src = lo & 0xFFFF;
    int local = (lo >> 16) & 63;
    float ewf = __uint_as_float((u32)(v >> 32));
    int q = atomicAdd(&cur[local], 1);
    float w = ewf * dis[src] * disc[local];
    meta[q] = ((u64)__float_as_uint(w) << 32) | (u32)src;
  }
}

// ---------------- propagation (grouped dwordx4 gather, meta software-pipelined) ----------------
__global__ __launch_bounds__(256) void k_prop_bf(const int* __restrict__ rp, const u64* __restrict__ meta,
                                                 const u32* __restrict__ h, const u32* __restrict__ other,
                                                 u32* __restrict__ outb,
                                                 const float coefP, const float coefO) {
  const int node = blockIdx.x * 4 + (threadIdx.x >> 6);
  const int lane = threadIdx.x & 63;
  const int g = lane >> 4;          // edge group 0..3
  const int cq = lane & 15;         // u32-quad index within row
  if (node >= NN) return;
  const int j0 = rp[node], j1 = rp[node + 1];
  float a0 = 0.f, a1 = 0.f, a2 = 0.f, a3 = 0.f, a4 = 0.f, a5 = 0.f, a6 = 0.f, a7 = 0.f;
  if (j0 < j1) {
    int ji = j0 + g;
    u64 mnext = meta[(ji < j1) ? ji : (j1 - 1)];
#pragma unroll 4
    for (int j = j0; j < j1; j += 4) {
      const u64 m = mnext;
      const int jn = j + 4 + g;
      mnext = meta[(jn < j1) ? jn : (j1 - 1)];            // prefetch next stage
      const bool act = (j + g) < j1;
      const float w = act ? __uint_as_float((u32)(m >> 32)) : 0.f;
      const u32 src = (u32)m & 0xFFFFu;
      u32x4 v = *(const u32x4*)&h[(size_t)src * 64 + cq * 4];
      a0 = fmaf(w, bflo(v.x), a0); a1 = fmaf(w, bfhi(v.x), a1);
      a2 = fmaf(w, bflo(v.y), a2); a3 = fmaf(w, bfhi(v.y), a3);
      a4 = fmaf(w, bflo(v.z), a4); a5 = fmaf(w, bfhi(v.z), a5);
      a6 = fmaf(w, bflo(v.w), a6); a7 = fmaf(w, bfhi(v.w), a7);
    }
  }
  // reduce across the 4 edge groups
  a0 += __shfl_xor(a0, 16); a1 += __shfl_xor(a1, 16);
  a2 += __shfl_xor(a2, 16); a3 += __shfl_xor(a3, 16);
  a4 += __shfl_xor(a4, 16); a5 += __shfl_xor(a5, 16);
  a6 += __shfl_xor(a6, 16); a7 += __shfl_xor(a7, 16);
  a0 += __shfl_xor(a0, 32); a1 += __shfl_xor(a1, 32);
  a2 += __shfl_xor(a2, 32); a3 += __shfl_xor(a3, 32);
  a4 += __shfl_xor(a4, 32); a5 += __shfl_xor(a5, 32);
  a6 += __shfl_xor(a6, 32); a7 += __shfl_xor(a7, 32);
  if (lane < 16) {
    const size_t oi = (size_t)node * 64 + cq * 4;
    float o0 = 0.f, o1 = 0.f, o2 = 0.f, o3 = 0.f, o4 = 0.f, o5 = 0.f, o6 = 0.f, o7 = 0.f;
    if (other != nullptr) {
      u32x4 ov = *(const u32x4*)&other[oi];
      o0 = bflo(ov.x); o1 = bfhi(ov.x); o2 = bflo(ov.y); o3 = bfhi(ov.y);
      o4 = bflo(ov.z); o5 = bfhi(ov.z); o6 = bflo(ov.w); o7 = bfhi(ov.w);
    }
    u32x4 r;
    r.x = pack_bf2(fmaf(coefP, a0, coefO * o0), fmaf(coefP, a1, coefO * o1));
    r.y = pack_bf2(fmaf(coefP, a2, coefO * o2), fmaf(coefP, a3, coefO * o3));
    r.z = pack_bf2(fmaf(coefP, a4, coefO * o4), fmaf(coefP, a5, coefO * o5));
    r.w = pack_bf2(fmaf(coefP, a6, coefO * o6), fmaf(coefP, a7, coefO * o7));
    *(u32x4*)&outb[oi] = r;
  }
}

// ---------------- fused 4-output MFMA GEMM (streamed basis tiles) ----------------
// 32 rows/block, 4 waves (wave w -> cols w*32..w*32+31).
__global__ __launch_bounds__(256, 4) void k_gemm_all(
    const u16* __restrict__ xb, const u16* __restrict__ t1,
    const u16* __restrict__ t2, const u16* __restrict__ t3,
    const u16* __restrict__ Wp,
    const float* __restrict__ b0, const float* __restrict__ b1,
    const float* __restrict__ b2, const float* __restrict__ b3,
    float* __restrict__ out) {
  __shared__ __align__(16) char ldsb[2][8192];   // 2 x 32 rows x 256 B
  const int tid = threadIdx.x;
  const int w = tid >> 6, lane = tid & 63;
  const int rowg0 = blockIdx.x * 32;
  const u16* bases[4] = {xb, t1, t2, t3};
  const int mbase[4] = {0, 1, 3, 6};

  const int c0 = tid,        r_0 = c0 >> 4, s_0 = (c0 & 15) << 4;
  const int c1 = 256 + tid,  r_1 = c1 >> 4, s_1 = (c1 & 15) << 4;

  f32x4 acc[4][2][2];
#pragma unroll
  for (int k = 0; k < 4; ++k)
#pragma unroll
    for (int rf = 0; rf < 2; ++rf)
#pragma unroll
      for (int c = 0; c < 2; ++c) acc[k][rf][c] = (f32x4){0.f, 0.f, 0.f, 0.f};

  // prologue: stage tile 0
  {
    u16x8 v0 = {0,0,0,0,0,0,0,0}, v1 = {0,0,0,0,0,0,0,0};
    if (rowg0 + r_0 < NN) v0 = *(const u16x8*)((const char*)bases[0] + (size_t)(rowg0 + r_0) * 256 + s_0);
    if (rowg0 + r_1 < NN) v1 = *(const u16x8*)((const char*)bases[0] + (size_t)(rowg0 + r_1) * 256 + s_1);
    *(u16x8*)(&ldsb[0][r_0 * 256 + (s_0 ^ ((r_0 & 7) << 4))]) = v0;
    *(u16x8*)(&ldsb[0][r_1 * 256 + (s_1 ^ ((r_1 & 7) << 4))]) = v1;
  }
  __syncthreads();

#pragma unroll
  for (int i = 0; i < 4; ++i) {
    u16x8 nv0 = {0,0,0,0,0,0,0,0}, nv1 = {0,0,0,0,0,0,0,0};
    if (i < 3) {
      if (rowg0 + r_0 < NN) nv0 = *(const u16x8*)((const char*)bases[i + 1] + (size_t)(rowg0 + r_0) * 256 + s_0);
      if (rowg0 + r_1 < NN) nv1 = *(const u16x8*)((const char*)bases[i + 1] + (size_t)(rowg0 + r_1) * 256 + s_1);
    }

    const char* tile = ldsb[i & 1];
#pragma unroll
    for (int ks = 0; ks < 4; ++ks) {
      const int kb = ks * 64 + ((lane >> 4) << 4);
      const int r0 = (lane & 15), r1 = 16 + (lane & 15);
      const bf16x8 a0 = __builtin_bit_cast(bf16x8,
          *(const u16x8*)(tile + r0 * 256 + (kb ^ ((r0 & 7) << 4))));
      const bf16x8 a1 = __builtin_bit_cast(bf16x8,
          *(const u16x8*)(tile + r1 * 256 + (kb ^ ((r1 & 7) << 4))));
#pragma unroll
      for (int k = 3; k >= 0; --k) {
        if (k < i) continue;
        const int m = mbase[k] + i;
        const bf16x8 bf0 = __builtin_bit_cast(bf16x8,
            *(const u16x8*)(Wp + (size_t)((m * 4 + ks) * 8 + (w * 2 + 0)) * 512 + lane * 8));
        const bf16x8 bf1 = __builtin_bit_cast(bf16x8,
            *(const u16x8*)(Wp + (size_t)((m * 4 + ks) * 8 + (w * 2 + 1)) * 512 + lane * 8));
        acc[k][0][0] = __builtin_amdgcn_mfma_f32_16x16x32_bf16(a0, bf0, acc[k][0][0], 0, 0, 0);
        acc[k][1][0] = __builtin_amdgcn_mfma_f32_16x16x32_bf16(a1, bf0, acc[k][1][0], 0, 0, 0);
        acc[k][0][1] = __builtin_amdgcn_mfma_f32_16x16x32_bf16(a0, bf1, acc[k][0][1], 0, 0, 0);
        acc[k][1][1] = __builtin_amdgcn_mfma_f32_16x16x32_bf16(a1, bf1, acc[k][1][1], 0, 0, 0);
      }
    }
    if (i < 3) {
      char* nb = ldsb[(i + 1) & 1];
      *(u16x8*)(&nb[r_0 * 256 + (s_0 ^ ((r_0 & 7) << 4))]) = nv0;
      *(u16x8*)(&nb[r_1 * 256 + (s_1 ^ ((r_1 & 7) << 4))]) = nv1;
    }
    __syncthreads();
  }

  // epilogue: bias + relu + fp32 store.  C/D: col=lane&15, row=(lane>>4)*4+j
  const float* biases[4] = {b0, b1, b2, b3};
  const int colb = w * 32;
#pragma unroll
  for (int k = 0; k < 4; ++k) {
    const float bv0 = biases[k][colb + (lane & 15)];
    const float bv1 = biases[k][colb + 16 + (lane & 15)];
    float* ok = out + (size_t)k * NN * CH;
#pragma unroll
    for (int rf = 0; rf < 2; ++rf) {
#pragma unroll
      for (int j = 0; j < 4; ++j) {
        const int row = rowg0 + rf * 16 + ((lane >> 4) << 2) + j;
        if (row < NN) {
          ok[(size_t)row * CH + colb + (lane & 15)]      = fmaxf(acc[k][rf][0][j] + bv0, 0.f);
          ok[(size_t)row * CH + colb + 16 + (lane & 15)] = fmaxf(acc[k][rf][1][j] + bv1, 0.f);
        }
      }
    }
  }
}

// ---------------- launch ----------------
static inline size_t align256(size_t x) { return (x + 255) & ~(size_t)255; }

extern "C" void kernel_launch(void* const* d_in, const int* in_sizes, int n_in,
                              void* d_out, int out_size, void* d_ws, size_t ws_size,
                              hipStream_t stream) {
  const float* x  = (const float*)d_in[0];
  const int*   ei = (const int*)d_in[1];
  const float* ew = (const float*)d_in[2];
  const float* W[4]  = {(const float*)d_in[3], (const float*)d_in[5],
                        (const float*)d_in[7], (const float*)d_in[9]};
  const float* bs[4] = {(const float*)d_in[4], (const float*)d_in[6],
                        (const float*)d_in[8], (const float*)d_in[10]};
  float* out = (float*)d_out;

  char* ws = (char*)d_ws;
  size_t off = 0;
  auto alloc = [&](size_t bytes) -> void* { void* p = ws + off; off = align256(off + bytes); return p; };
  float* dis      = (float*)alloc(sizeof(float) * NN);
  int*   rp       = (int*)alloc(sizeof(int) * (NN + 1));
  int*   hist     = (int*)alloc(sizeof(int) * MH);
  int*   partials = (int*)alloc(sizeof(int) * 1024);
  int*   part     = (int*)alloc(sizeof(int) * (size_t)DC * NN);
  u64*   sorted   = (u64*)alloc(sizeof(u64) * NE);
  u64*   meta     = (u64*)alloc(sizeof(u64) * NE);
  u32*   xb       = (u32*)alloc(sizeof(u32) * (size_t)NN * 64);
  u32*   t1b      = (u32*)alloc(sizeof(u32) * (size_t)NN * 64);
  u32*   t2b      = (u32*)alloc(sizeof(u32) * (size_t)NN * 64);
  u32*   t3b      = (u32*)alloc(sizeof(u32) * (size_t)NN * 64);
  u16*   Wp       = (u16*)alloc(sizeof(u16) * 10 * 4 * 8 * 64 * 8);
  (void)ws_size; (void)in_sizes; (void)n_in; (void)out_size;

  // front: row-deg + col-hist + conversions (independent, one launch)
  k_front<<<FRONT_BLOCKS, 256, 0, stream>>>(ei, ew, part, hist, x, xb,
                                            W[0], W[1], W[2], W[3], Wp);

  // CSR build (counting sort); degred rides in the scan1 launch
  k_scan1d<<<G1 + DEGRED_BLOCKS, 256, 0, stream>>>(hist, partials, part, dis);
  k_scan2<<<1, 256, 0, stream>>>(partials);
  k_scan3<<<G1, 256, 0, stream>>>(hist, partials);
  kC<<<BH, 256, 0, stream>>>(ei, ew, hist, sorted);
  kD<<<NBUCK, 256, 0, stream>>>(sorted, hist, dis, rp, meta);

  // basis: Tx1 = -P(x); Tx2 = -1.5 P(Tx1) - 0.5 x; Tx3 = -(5/3) P(Tx2) - (2/3) Tx1
  k_prop_bf<<<12500, 256, 0, stream>>>(rp, meta, xb, nullptr, t1b, -1.f, 0.f);
  k_prop_bf<<<12500, 256, 0, stream>>>(rp, meta, t1b, xb, t2b, -1.5f, -0.5f);
  k_prop_bf<<<12500, 256, 0, stream>>>(rp, meta, t2b, t1b, t3b, -5.f / 3.f, -2.f / 3.f);

  // fused 4-output GEMM with bias+relu (32-row blocks)
  k_gemm_all<<<(NN + 31) / 32, 256, 0, stream>>>(
      (const u16*)xb, (const u16*)t1b, (const u16*)t2b, (const u16*)t3b,
      Wp, bs[0], bs[1], bs[2], bs[3], out);
}